// Round 1
// baseline (68.911 us; speedup 1.0000x reference)
//
#include <hip/hip_runtime.h>

typedef float f32x4 __attribute__((ext_vector_type(4)));
typedef _Float16 half8 __attribute__((ext_vector_type(8)));

#define NEG 0.2f

// ---------------------------------------------------------------------------
// K1: Wh = nf @ W^T (f32), s1 = Wh@a1, s2 = Wh@a2 (exact f32),
//     per-block max(s2) -> smax slots, Wh -> fp16 transposed [b][o][j].
// grid 256 = 8 batches x 32 row-blocks of 64 rows; block 256 (4 waves).
// ---------------------------------------------------------------------------
__global__ __launch_bounds__(256) void gat_wh_kernel(
    const float* __restrict__ nf, const float* __restrict__ W,
    const float* __restrict__ a, _Float16* __restrict__ whT,
    float* __restrict__ s1g, float* __restrict__ s2g, float* __restrict__ smax)
{
    const int b    = blockIdx.x >> 5;
    const int rb   = blockIdx.x & 31;
    const int row0 = rb * 64;
    const int t    = threadIdx.x;
    const int lane = t & 63;
    const int wv   = t >> 6;

    __shared__ _Float16 whL[64][72];   // [row][o], pad to 72 to spread banks
    __shared__ float    wred[4];

    // W row (o = lane) in registers: 64 VGPRs
    f32x4 Wreg[16];
    const float* wp = W + lane * 64;
#pragma unroll
    for (int i = 0; i < 16; ++i) Wreg[i] = *(const f32x4*)(wp + i * 4);
    const float a1v = a[lane];
    const float a2v = a[64 + lane];

    const float* nfb = nf + ((long)b * 2048 + row0) * 64;
    float wmax = -3.0e38f;

    for (int g = 0; g < 16; ++g) {
        const int row = g * 4 + wv;
        const f32x4* nfp = (const f32x4*)(nfb + row * 64);  // same addr across wave -> broadcast
        f32x4 acc = {0.f, 0.f, 0.f, 0.f};
#pragma unroll
        for (int i = 0; i < 16; ++i) acc += nfp[i] * Wreg[i];
        const float wh = acc.x + acc.y + acc.z + acc.w;     // Wh[row][lane]
        whL[row][lane] = (_Float16)wh;
        float p1 = wh * a1v;
        float p2 = wh * a2v;
#pragma unroll
        for (int m = 32; m >= 1; m >>= 1) {
            p1 += __shfl_xor(p1, m);
            p2 += __shfl_xor(p2, m);
        }
        if (lane == 0) {
            s1g[b * 2048 + row0 + row] = p1;
            s2g[b * 2048 + row0 + row] = p2;
            wmax = fmaxf(wmax, p2);
        }
    }
    if (lane == 0) wred[wv] = wmax;
    __syncthreads();
    if (t == 0)
        smax[blockIdx.x] = fmaxf(fmaxf(wred[0], wred[1]), fmaxf(wred[2], wred[3]));

    // transpose out: whT[(b*64+o)*2048 + row0 + j]
    const int o = t >> 2;
    const int part = t & 3;
    unsigned int tmp[8];
#pragma unroll
    for (int kk = 0; kk < 8; ++kk) {
        const int j = part * 16 + kk * 2;
        unsigned int lo = *(const unsigned short*)&whL[j][o];
        unsigned int hi = *(const unsigned short*)&whL[j + 1][o];
        tmp[kk] = lo | (hi << 16);
    }
    uint4 v0, v1;
    v0.x = tmp[0]; v0.y = tmp[1]; v0.z = tmp[2]; v0.w = tmp[3];
    v1.x = tmp[4]; v1.y = tmp[5]; v1.z = tmp[6]; v1.w = tmp[7];
    _Float16* dst = whT + ((long)(b * 64 + o) * 2048 + row0 + part * 16);
    *(uint4*)dst = v0;
    *(uint4*)(dst + 8) = v1;
}

// ---------------------------------------------------------------------------
// K2: per 32-row tile: denom pass (row max closed-form via batch max of s2),
//     then 32 x K=64 chunks: P tile -> global f32 attention + fp16 LDS,
//     PV via mfma_f32_16x16x32_f16, elu epilogue.
// grid 512 = 8 batches x 64 row-blocks of 32; block 256 (4 waves).
// ---------------------------------------------------------------------------
__global__ __launch_bounds__(256) void gat_attn_kernel(
    const _Float16* __restrict__ whT, const float* __restrict__ s1g,
    const float* __restrict__ s2g, const float* __restrict__ smax,
    float* __restrict__ outp)
{
    const int b    = blockIdx.x >> 6;
    const int rb   = blockIdx.x & 63;
    const int i0   = rb * 32;
    const int t    = threadIdx.x;
    const int lane = t & 63;
    const int wv   = t >> 6;

    __shared__ __attribute__((aligned(16))) float s2sh[2048];
    __shared__ float s1sh[32], Msh[32], iDsh[32];
    __shared__ float m2sh;
    __shared__ __attribute__((aligned(16))) _Float16 Pl[32][72];
    __shared__ __attribute__((aligned(16))) _Float16 WhL[64][72];

    // ---- phase 0: stage s2 (full batch row), s1 tile, m2 = max(s2) ----
#pragma unroll
    for (int k = 0; k < 8; ++k) s2sh[t + k * 256] = s2g[b * 2048 + t + k * 256];
    if (t < 32) {
        s1sh[t] = s1g[b * 2048 + i0 + t];
        float v = smax[b * 32 + t];
#pragma unroll
        for (int m = 16; m >= 1; m >>= 1) v = fmaxf(v, __shfl_xor(v, m));
        if (t == 0) m2sh = v;
    }
    __syncthreads();

    // ---- phase 1: denominators. M_i = lrelu(s1_i + max_j s2_j) exactly ----
    {
        const float m2  = m2sh;
        const int   r   = t >> 3, q = t & 7;
        const float s1r = s1sh[r];
        const float xm  = s1r + m2;
        const float M   = fmaxf(xm, NEG * xm);
        float acc = 0.f;
        for (int j = q; j < 2048; j += 8) {
            float x = s1r + s2sh[j];
            float e = fmaxf(x, NEG * x);
            acc += __expf(e - M);
        }
        acc += __shfl_xor(acc, 1);
        acc += __shfl_xor(acc, 2);
        acc += __shfl_xor(acc, 4);
        if (q == 0) { Msh[r] = M; iDsh[r] = 1.0f / acc; }
    }
    __syncthreads();

    // ---- phase 2: K loop ----
    f32x4 acc0 = {0.f, 0.f, 0.f, 0.f}, acc1 = {0.f, 0.f, 0.f, 0.f};
    const int h  = wv & 1;          // row half (16 rows)
    const int cb = (wv >> 1) * 32;  // col base (32 cols, 2 subtiles)
    float* attnb = outp + 1048576 + ((long)b * 2048 + i0) * 2048;
    const _Float16* whTb = whT + (long)b * 64 * 2048;
    const int so = t >> 2, sp = t & 3;  // staging: o-row, 16j-part

    for (int c = 0; c < 32; ++c) {
        const int j0 = c * 64;
        // stage Wh^T chunk [o][j0..j0+63] -> WhL (8 KB)
        {
            const uint4* src = (const uint4*)(whTb + (long)so * 2048 + j0 + sp * 16);
            uint4 w0 = src[0], w1 = src[1];
            *(uint4*)&WhL[so][sp * 16]     = w0;
            *(uint4*)&WhL[so][sp * 16 + 8] = w1;
        }
        // compute P tile: wave wv covers rows {wv, wv+4, ...}, j = lane
        const float sv = s2sh[j0 + lane];
#pragma unroll
        for (int k = 0; k < 8; ++k) {
            const int r = wv + k * 4;
            float x = s1sh[r] + sv;
            float e = fmaxf(x, NEG * x);
            float p = __expf(e - Msh[r]) * iDsh[r];
            attnb[(long)r * 2048 + j0 + lane] = p;   // coalesced f32 store
            Pl[r][lane] = (_Float16)p;
        }
        __syncthreads();
        // MFMA: out[16x16] subtiles; A = P (MxK), B = Wh (KxN)
        {
            const int arow  = h * 16 + (lane & 15);
            const int koff  = (lane >> 4) * 8;
            const int brow0 = cb + (lane & 15);
#pragma unroll
            for (int kc = 0; kc < 2; ++kc) {
                half8 av  = *(const half8*)&Pl[arow][kc * 32 + koff];
                half8 bv0 = *(const half8*)&WhL[brow0][kc * 32 + koff];
                half8 bv1 = *(const half8*)&WhL[brow0 + 16][kc * 32 + koff];
                acc0 = __builtin_amdgcn_mfma_f32_16x16x32_f16(av, bv0, acc0, 0, 0, 0);
                acc1 = __builtin_amdgcn_mfma_f32_16x16x32_f16(av, bv1, acc1, 0, 0, 0);
            }
        }
        __syncthreads();
    }

    // ---- epilogue: elu, write out0 ----
    {
        const int col = lane & 15;
        const int rg  = lane >> 4;
        float* ob = outp + ((long)b * 2048 + i0 + h * 16 + rg * 4) * 64 + cb + col;
#pragma unroll
        for (int r = 0; r < 4; ++r) {
            float x = acc0[r];
            ob[r * 64] = (x > 0.f) ? x : (__expf(x) - 1.0f);
            float y = acc1[r];
            ob[r * 64 + 16] = (y > 0.f) ? y : (__expf(y) - 1.0f);
        }
    }
}

extern "C" void kernel_launch(void* const* d_in, const int* in_sizes, int n_in,
                              void* d_out, int out_size, void* d_ws, size_t ws_size,
                              hipStream_t stream)
{
    (void)in_sizes; (void)n_in; (void)out_size; (void)ws_size;
    const float* nf = (const float*)d_in[0];
    const float* W  = (const float*)d_in[1];
    const float* a  = (const float*)d_in[2];
    float* outp = (float*)d_out;

    char* ws = (char*)d_ws;
    _Float16* whT = (_Float16*)ws;                         // 2 MB: [8][64][2048] fp16
    float* s1g  = (float*)(ws + 2097152);                  // 64 KB
    float* s2g  = (float*)(ws + 2097152 + 65536);          // 64 KB
    float* smax = (float*)(ws + 2097152 + 131072);         // 256 slots

    gat_wh_kernel<<<256, 256, 0, stream>>>(nf, W, a, whT, s1g, s2g, smax);
    gat_attn_kernel<<<512, 256, 0, stream>>>(whT, s1g, s2g, smax, outp);
}